// Round 3
// baseline (1308.019 us; speedup 1.0000x reference)
//
#include <hip/hip_runtime.h>
#include <stdint.h>

#define NB 4
#define QL 2048
#define KL 2048
#define HEADS 16
#define EMB 1024
#define HD 64

typedef float f32x2 __attribute__((ext_vector_type(2)));
typedef float f32x4 __attribute__((ext_vector_type(4)));
typedef float f32x16 __attribute__((ext_vector_type(16)));
typedef __bf16 bf16x2 __attribute__((ext_vector_type(2)));
typedef __bf16 bf16x8 __attribute__((ext_vector_type(8)));
typedef unsigned short u16x8 __attribute__((ext_vector_type(8)));
typedef unsigned short u16x4 __attribute__((ext_vector_type(4)));
typedef unsigned int u32x4 __attribute__((ext_vector_type(4)));

static __device__ __forceinline__ unsigned short f2bf(float f) {
  unsigned u = __float_as_uint(f);
  u += 0x7fffu + ((u >> 16) & 1u);
  return (unsigned short)(u >> 16);
}
static __device__ __forceinline__ float bf2f(unsigned short h) {
  return __uint_as_float(((unsigned)h) << 16);
}
static __device__ __forceinline__ float fast_exp2(float x) {
#if __has_builtin(__builtin_amdgcn_exp2f)
  return __builtin_amdgcn_exp2f(x);
#else
  return __expf(x * 0.6931471805599453f);
#endif
}
static __device__ __forceinline__ float fast_rcp(float x) {
#if __has_builtin(__builtin_amdgcn_rcpf)
  return __builtin_amdgcn_rcpf(x);
#else
  return 1.0f / x;
#endif
}
static __device__ __forceinline__ void dma16(const void* g, void* l) {
  __builtin_amdgcn_global_load_lds(
      (const __attribute__((address_space(1))) unsigned int*)(uintptr_t)g,
      (__attribute__((address_space(3))) unsigned int*)(uintptr_t)l, 16, 0, 0);
}
static __device__ __forceinline__ void dma4(const void* g, void* l) {
  __builtin_amdgcn_global_load_lds(
      (const __attribute__((address_space(1))) unsigned int*)(uintptr_t)g,
      (__attribute__((address_space(3))) unsigned int*)(uintptr_t)l, 4, 0, 0);
}
static __device__ __forceinline__ void barrier_plain() {
  __asm__ volatile("" ::: "memory");
  __builtin_amdgcn_s_barrier();
  __asm__ volatile("" ::: "memory");
}
#define WAITVM(N) __asm__ volatile("s_waitcnt vmcnt(" #N ")" ::: "memory")

// ---- ws layout (bytes) ----
#define XHI_OFF  0ull
#define XLO_OFF  16777216ull
#define KHI_OFF  33554432ull
#define VT_OFF   50331648ull
#define WHI_OFF  67108864ull
#define WLO_OFF  69206016ull
#define MB_OFF   71303168ull

// QSC = (1/32) * log2(e); exp2 shift = 8*log2(e)
#define QSC  0.0450842399f
#define ESHIFT 11.5415601730f

// ---------------- fused prep (unchanged) ----------------
__global__ __launch_bounds__(256) void prep_all(const float* __restrict__ Kg,
                                                const float* __restrict__ Vg,
                                                const float* __restrict__ Wg,
                                                const int* __restrict__ Mg,
                                                unsigned short* __restrict__ Khi,
                                                unsigned short* __restrict__ Vt,
                                                unsigned short* __restrict__ Whi,
                                                unsigned short* __restrict__ Wlo,
                                                unsigned long long* __restrict__ bits) {
  __shared__ unsigned short lds[64 * 66];
  const int tid = threadIdx.x;
  const int bid = blockIdx.x;
  if (bid < 8192) {
    // K f32 -> bf16 tiles [n][h][kt]{row=kvl, 128B rows, chunk c stored at c^(row&7)}
    int t = bid * 256 + tid;
    int d4 = t & 15, h = (t >> 4) & 15, kv = (t >> 8) & 2047, n = t >> 19;
    f32x4 a = *(const f32x4*)(Kg + (size_t)(n * KL + kv) * EMB + h * 64 + d4 * 4);
    u16x4 o;
    #pragma unroll
    for (int j = 0; j < 4; ++j) o[j] = f2bf(a[j]);
    int row = kv & 63, c0 = d4 >> 1;
    int pos = row * 128 + ((c0 ^ (row & 7)) << 4) + (d4 & 1) * 8;
    size_t slab = (size_t)((n * 16 + h) * 32 + (kv >> 6)) * 8192;
    *(u16x4*)((char*)Khi + slab + pos) = o;
  } else if (bid < 10240) {
    // V -> V^T bf16 tiles, pi(kv) column permute (swap bits 2<->3), fetch-swizzled rows
    int vb = bid - 8192;
    int kt = vb & 31, h = (vb >> 5) & 15, n = vb >> 9;
    #pragma unroll
    for (int i = 0; i < 4; ++i) {
      int e = i * 256 + tid;
      int d4 = e & 15, kvl = e >> 4;
      int col = (kvl & 48) | (kvl & 3) | ((kvl & 4) << 1) | ((kvl & 8) >> 1);
      f32x4 a = *(const f32x4*)(Vg + (size_t)(n * KL + kt * 64 + kvl) * EMB + h * 64 + d4 * 4);
      #pragma unroll
      for (int j = 0; j < 4; ++j) lds[(d4 * 4 + j) * 66 + col] = f2bf(a[j]);
    }
    __syncthreads();
    size_t slab = (size_t)((n * 16 + h) * 32 + kt) * 8192;
    #pragma unroll
    for (int i = 0; i < 4; ++i) {
      int e = i * 256 + tid;
      int kv4 = e & 15, d = e >> 4;
      u16x4 o;
      #pragma unroll
      for (int j = 0; j < 4; ++j) o[j] = lds[d * 66 + kv4 * 4 + j];
      int c0 = kv4 >> 1;
      int pos = d * 128 + ((c0 ^ (d & 7)) << 4) + (kv4 & 1) * 8;
      *(u16x4*)((char*)Vt + slab + pos) = o;
    }
  } else if (bid < 11264) {
    // W -> hi/lo split, flat
    int t = (bid - 10240) * 256 + tid;
    int c4 = t & 255, row = t >> 8;
    f32x4 a = *(const f32x4*)(Wg + (size_t)row * 1024 + c4 * 4);
    u16x4 hi, lo;
    #pragma unroll
    for (int j = 0; j < 4; ++j) {
      unsigned short hb = f2bf(a[j]);
      hi[j] = hb;
      lo[j] = f2bf(a[j] - bf2f(hb));
    }
    *(u16x4*)(Whi + (size_t)row * 1024 + c4 * 4) = hi;
    *(u16x4*)(Wlo + (size_t)row * 1024 + c4 * 4) = lo;
  } else {
    // mask int32 -> bit words, relaid out [n][qb(8)][kt(32)][q(256)]; 2 words per wave
    int t = (bid - 11264) * 256 + tid;
    int l = t & 63;
    int W = t >> 6;                       // wave id: 0..131071
    int kw2 = (W & 15) * 2;
    int row = W >> 4;                     // n*QL + q
    const int* mp = Mg + (size_t)row * KL;
    int v0 = mp[kw2 * 64 + l];
    int v1 = mp[kw2 * 64 + 64 + l];
    unsigned long long b0 = __ballot(v0 != 0);
    unsigned long long b1 = __ballot(v1 != 0);
    int q = row & 2047, nn = row >> 11;
    size_t base = (size_t)((nn * 8 + (q >> 8)) * 32) * 256 + (q & 255);
    if (l == 0) {
      bits[base + (size_t)kw2 * 256] = b0;
      bits[base + (size_t)(kw2 + 1) * 256] = b1;
    }
  }
}

// ---------------- flash attention: S^T trick, 64 q per wave, 4 blocks/CU ----------------
// Round-0 structure (4 waves x 64 q = 256 q/block, 2-buffer, two barriers/step):
// per-q LDS/DMA/VALU amortization of the 107us baseline. New: LDS is only 36.9KB
// so __launch_bounds__(256,4) fits 4 blocks/CU -> 4 waves/SIMD from FOUR
// independent barrier groups (phase diversity without per-q cost), + XCD swizzle
// (proven FETCH 148->53MB) + setprio around MFMA clusters.
__global__ __launch_bounds__(256, 4) void attn4(const float* __restrict__ Qg,
                                                const unsigned short* __restrict__ Khi,
                                                const unsigned short* __restrict__ Vt,
                                                const unsigned long long* __restrict__ Mb,
                                                unsigned short* __restrict__ Xhi,
                                                unsigned short* __restrict__ Xlo) {
  __shared__ __align__(16) char smem[2 * 18432];  // per buf: K 8K | V 8K | M 2K
  const int tid = threadIdx.x;
  const int w = tid >> 6;
  const int l = tid & 63;
  const int q32 = l & 31;
  const int h5 = l >> 5;
  const int bid0 = blockIdx.x;
  // bijective XCD swizzle: 512 blocks % 8 == 0; each XCD gets 64 contiguous
  // logical blocks = 8 (n,h) K/V slab pairs (4MB) -> per-XCD L2 resident
  const int bid = (bid0 & 7) * 64 + (bid0 >> 3);
  const int qb = bid & 7;
  const int h = (bid >> 3) & 15;
  const int n = bid >> 7;
  const int qbase = qb * 256 + w * 64;

  const char* kslab = (const char*)Khi + (size_t)(n * HEADS + h) * 262144;
  const char* vslab = (const char*)Vt + (size_t)(n * HEADS + h) * 262144;
  const char* mslab = (const char*)Mb + (size_t)(n * 8 + qb) * 65536;

  // Q fragments (B-operand), prescaled by QSC; two 32-q column groups per wave
  bf16x8 qh[2][4];
  #pragma unroll
  for (int c = 0; c < 2; ++c) {
    const float* qp = Qg + (size_t)(n * QL + qbase + c * 32 + q32) * EMB + h * HD + h5 * 8;
    #pragma unroll
    for (int kc = 0; kc < 4; ++kc) {
      union { u16x8 u; bf16x8 b; } H;
      #pragma unroll
      for (int j = 0; j < 8; ++j) H.u[j] = f2bf(qp[kc * 16 + j] * QSC);
      qh[c][kc] = H.b;
    }
  }
  WAITVM(0);  // no VGPR-returning vmem outstanding before DMA pipeline starts

  // hoisted LDS offsets: off8[r2][g] for row = r2*32+q32, chunk G = 2g+h5
  int off8[2][4];
  #pragma unroll
  for (int r2 = 0; r2 < 2; ++r2)
    #pragma unroll
    for (int g = 0; g < 4; ++g)
      off8[r2][g] = (r2 * 32 + q32) * 128 + (((2 * g + h5) ^ (q32 & 7)) << 4);

  f32x16 o00, o01, o10, o11, l0, l1;
  #pragma unroll
  for (int i = 0; i < 16; ++i) {
    o00[i] = 0.f; o01[i] = 0.f; o10[i] = 0.f; o11[i] = 0.f; l0[i] = 0.f; l1[i] = 0.f;
  }

  union { u16x8 u; bf16x8 b; } O1;
  #pragma unroll
  for (int j = 0; j < 8; ++j) O1.u[j] = 0x3F80;  // bf16 1.0
  const bf16x8 ones = O1.b;

  auto issue = [&](int kt, char* buf) {
    const char* ks = kslab + kt * 8192 + w * 2048 + l * 16;
    const char* vs = vslab + kt * 8192 + w * 2048 + l * 16;
    dma16(ks, buf + w * 2048);
    dma16(ks + 1024, buf + w * 2048 + 1024);
    dma16(vs, buf + 8192 + w * 2048);
    dma16(vs + 1024, buf + 8192 + w * 2048 + 1024);
    const char* ms = mslab + kt * 2048 + w * 512 + l * 4;
    dma4(ms, buf + 16384 + w * 512);
    dma4(ms + 256, buf + 16384 + w * 512 + 256);
  };

  auto step = [&](int kt, char* cur, char* nxt) {
    barrier_plain();                       // everyone done reading nxt's old tile
    if (kt != 31) {
      issue(kt + 1, nxt);
      WAITVM(6);                           // drain tile kt's 6 DMAs, keep kt+1's 6
    } else {
      WAITVM(0);
    }
    barrier_plain();                       // publish tile kt
    unsigned long long mwc0 = *(const unsigned long long*)(cur + 16384 + (w * 64 + q32) * 8);
    unsigned long long mwc1 = *(const unsigned long long*)(cur + 16384 + (w * 64 + 32 + q32) * 8);

    #pragma unroll
    for (int Mt = 0; Mt < 2; ++Mt) {
      // K fragments: shared across both q-groups
      union { u16x8 u; bf16x8 b; } kf[4];
      #pragma unroll
      for (int kc = 0; kc < 4; ++kc) kf[kc].u = *(const u16x8*)(cur + off8[Mt][kc]);

      unsigned int pk0[8], pk1[8];
      #pragma unroll
      for (int c = 0; c < 2; ++c) {
        f32x16 st;
        #pragma unroll
        for (int i = 0; i < 16; ++i) st[i] = -ESHIFT;   // fold exp2 shift into C-init
        __builtin_amdgcn_s_setprio(1);
        #pragma unroll
        for (int kc = 0; kc < 4; ++kc)
          st = __builtin_amdgcn_mfma_f32_32x32x16_bf16(kf[kc].b, qh[c][kc], st, 0, 0, 0);
        __builtin_amdgcn_s_setprio(0);
        unsigned long long mwc = c ? mwc1 : mwc0;
        unsigned int half = (unsigned int)(Mt ? (mwc >> 32) : mwc) >> (h5 * 4);
        unsigned int* pk = c ? pk1 : pk0;
        #pragma unroll
        for (int i = 0; i < 8; ++i) {
          const int r0 = 2 * i;
          const int b0 = (r0 & 3) + 8 * (r0 >> 2);
          float a0 = ((half >> b0) & 1u) ? st[r0] : -1.0e38f;
          float a1 = ((half >> (b0 + 1)) & 1u) ? st[r0 + 1] : -1.0e38f;
          float p0 = fast_exp2(a0);
          float p1 = fast_exp2(a1);
          bf16x2 pv = __builtin_convertvector((f32x2){p0, p1}, bf16x2);
          unsigned int u;
          __builtin_memcpy(&u, &pv, 4);
          pk[i] = u;
        }
      }
      #pragma unroll
      for (int kc2 = 0; kc2 < 2; ++kc2) {
        const int kvc = Mt * 2 + kc2;
        union { u16x8 u; bf16x8 b; } vf0, vf1;   // shared across both q-groups
        vf0.u = *(const u16x8*)(cur + 8192 + off8[0][kvc]);
        vf1.u = *(const u16x8*)(cur + 8192 + off8[1][kvc]);
        union { u32x4 wv; bf16x8 b; } pf0, pf1;
        #pragma unroll
        for (int j = 0; j < 4; ++j) {
          pf0.wv[j] = pk0[4 * kc2 + j];
          pf1.wv[j] = pk1[4 * kc2 + j];
        }
        __builtin_amdgcn_s_setprio(1);
        o00 = __builtin_amdgcn_mfma_f32_32x32x16_bf16(pf0.b, vf0.b, o00, 0, 0, 0);
        o01 = __builtin_amdgcn_mfma_f32_32x32x16_bf16(pf0.b, vf1.b, o01, 0, 0, 0);
        l0  = __builtin_amdgcn_mfma_f32_32x32x16_bf16(pf0.b, ones,  l0,  0, 0, 0);
        o10 = __builtin_amdgcn_mfma_f32_32x32x16_bf16(pf1.b, vf0.b, o10, 0, 0, 0);
        o11 = __builtin_amdgcn_mfma_f32_32x32x16_bf16(pf1.b, vf1.b, o11, 0, 0, 0);
        l1  = __builtin_amdgcn_mfma_f32_32x32x16_bf16(pf1.b, ones,  l1,  0, 0, 0);
        __builtin_amdgcn_s_setprio(0);
      }
    }
  };

  issue(0, smem);
  for (int kt2 = 0; kt2 < 16; ++kt2) {
    step(2 * kt2, smem, smem + 18432);
    step(2 * kt2 + 1, smem + 18432, smem);
  }

  // epilogue: per-reg l from ones-MFMA, rcp, split hi/lo
  #pragma unroll
  for (int c = 0; c < 2; ++c) {
    const f32x16& oa = c ? o10 : o00;
    const f32x16& ob = c ? o11 : o01;
    const f32x16& ll = c ? l1 : l0;
    #pragma unroll
    for (int r = 0; r < 16; ++r) {
      float inv = fast_rcp(ll[r]);
      int qr = (r & 3) + 8 * (r >> 2) + 4 * h5;
      size_t base = (size_t)(n * QL + qbase + c * 32 + qr) * EMB + h * HD + q32;
      float v0 = oa[r] * inv;
      unsigned short h0 = f2bf(v0);
      Xhi[base] = h0;
      Xlo[base] = f2bf(v0 - bf2f(h0));
      float v1 = ob[r] * inv;
      unsigned short h1 = f2bf(v1);
      Xhi[base + 32] = h1;
      Xlo[base + 32] = f2bf(v1 - bf2f(h1));
    }
  }
}

// ---------------- out = X @ W^T + b, split-bf16 3-term, manual dbuf pipeline ----------------
__global__ __launch_bounds__(256, 2) void proj3(const unsigned short* __restrict__ Xhi,
                                                const unsigned short* __restrict__ Xlo,
                                                const unsigned short* __restrict__ Whi,
                                                const unsigned short* __restrict__ Wlo,
                                                const float* __restrict__ bias,
                                                float* __restrict__ out) {
  __shared__ __align__(16) char pm[65536];   // 2 x (Ah|Al|Bh|Bl), 8KB each
  const int tid = threadIdx.x;
  const int w = tid >> 6;
  const int l = tid & 63;
  const int lr = l & 15;
  const int lq = l >> 4;
  const int wm = w >> 1, wn = w & 1;
  const int bid = blockIdx.x;
  const int m0 = (bid >> 3) * 128;
  const int n0 = (bid & 7) * 128;

  f32x4 acc[4][4];
  #pragma unroll
  for (int i = 0; i < 4; ++i)
    #pragma unroll
    for (int j = 0; j < 4; ++j) acc[i][j] = (f32x4){0.f, 0.f, 0.f, 0.f};

  auto issue = [&](int kc, char* buf) {
    #pragma unroll
    for (int i = 0; i < 8; ++i) {
      int s = (i * 256 + tid) * 16;
      int sel = s >> 13;
      int s2 = s & 8191;
      int row = s2 >> 6;
      int c = (s2 >> 4) & 3;
      const unsigned short* pl = sel == 0 ? Xhi : sel == 1 ? Xlo : sel == 2 ? Whi : Wlo;
      int rbase = (sel < 2 ? m0 : n0) + row;
      dma16(pl + (size_t)rbase * 1024 + kc * 32 + c * 8, buf + i * 4096 + w * 1024);
    }
  };

  auto pstep = [&](int kc, char* cur, char* nxt) {
    barrier_plain();
    if (kc != 31) {
      issue(kc + 1, nxt);
      WAITVM(8);
    } else {
      WAITVM(0);
    }
    barrier_plain();

    bf16x8 ah[4], al[4], bh[4], bl[4];
    #pragma unroll
    for (int mt = 0; mt < 4; ++mt) {
      int off = (wm * 64 + mt * 16 + lr) * 64 + lq * 16;
      union { u16x8 u; bf16x8 b; } A, B;
      A.u = *(const u16x8*)(cur + off);
      B.u = *(const u16x8*)(cur + 8192 + off);
      ah[mt] = A.b;
      al[mt] = B.b;
    }
    #pragma unroll
    for (int nt = 0; nt < 4; ++nt) {
      int off = (wn * 64 + nt * 16 + lr) * 64 + lq * 16;
      union { u16x8 u; bf16x8 b; } A, B;
      A.u = *(const u16x8*)(cur + 16384 + off);
      B.u = *(const u16x8*)(cur + 24576 + off);
      bh[nt] = A.b;
      bl[nt] = B.b;
    }
    #pragma unroll
    for (int mt = 0; mt < 4; ++mt)
      #pragma unroll
      for (int nt = 0; nt < 4; ++nt) {
        f32x4 c = acc[mt][nt];
        c = __builtin_amdgcn_mfma_f32_16x16x32_bf16(ah[mt], bh[nt], c, 0, 0, 0);
        c = __builtin_amdgcn_mfma_f32_16x16x32_bf16(ah[mt], bl[nt], c, 0, 0, 0);
        c = __builtin_amdgcn_mfma_f32_16x16x32_bf16(al[mt], bh[nt], c, 0, 0, 0);
        acc[mt][nt] = c;
      }
  };

  issue(0, pm);
  for (int kc2 = 0; kc2 < 16; ++kc2) {
    pstep(2 * kc2, pm, pm + 32768);
    pstep(2 * kc2 + 1, pm + 32768, pm);
  }

  #pragma unroll
  for (int nt = 0; nt < 4; ++nt) {
    int col = n0 + wn * 64 + nt * 16 + lr;
    float bv = bias[col];
    #pragma unroll
    for (int mt = 0; mt < 4; ++mt) {
      int rowb = m0 + wm * 64 + mt * 16 + lq * 4;
      #pragma unroll
      for (int r = 0; r < 4; ++r)
        out[(size_t)(rowb + r) * EMB + col] = acc[mt][nt][r] + bv;
    }
  }
}

extern "C" void kernel_launch(void* const* d_in, const int* in_sizes, int n_in,
                              void* d_out, int out_size, void* d_ws, size_t ws_size,
                              hipStream_t stream) {
  const float* Qg = (const float*)d_in[0];
  const float* Kg = (const float*)d_in[1];
  const float* Vg = (const float*)d_in[2];
  const int* Mg = (const int*)d_in[3];
  const float* Wg = (const float*)d_in[4];
  const float* Bg = (const float*)d_in[5];
  float* out = (float*)d_out;

  char* ws = (char*)d_ws;
  unsigned short* xhi = (unsigned short*)(ws + XHI_OFF);
  unsigned short* xlo = (unsigned short*)(ws + XLO_OFF);
  unsigned short* khi = (unsigned short*)(ws + KHI_OFF);
  unsigned short* vt = (unsigned short*)(ws + VT_OFF);
  unsigned short* whi = (unsigned short*)(ws + WHI_OFF);
  unsigned short* wlo = (unsigned short*)(ws + WLO_OFF);
  unsigned long long* mbits = (unsigned long long*)(ws + MB_OFF);

  prep_all<<<44032, 256, 0, stream>>>(Kg, Vg, Wg, Mg, khi, vt, whi, wlo, mbits);
  attn4<<<NB * HEADS * (QL / 256), 256, 0, stream>>>(Qg, khi, vt, mbits, xhi, xlo);
  proj3<<<(NB * QL / 128) * (EMB / 128), 256, 0, stream>>>(xhi, xlo, whi, wlo, Bg, out);
}

// Round 4
// 327.289 us; speedup vs baseline: 3.9965x; 3.9965x over previous
//
#include <hip/hip_runtime.h>
#include <stdint.h>

#define NB 4
#define QL 2048
#define KL 2048
#define HEADS 16
#define EMB 1024
#define HD 64

typedef float f32x2 __attribute__((ext_vector_type(2)));
typedef float f32x4 __attribute__((ext_vector_type(4)));
typedef float f32x16 __attribute__((ext_vector_type(16)));
typedef __bf16 bf16x2 __attribute__((ext_vector_type(2)));
typedef __bf16 bf16x8 __attribute__((ext_vector_type(8)));
typedef unsigned short u16x8 __attribute__((ext_vector_type(8)));
typedef unsigned short u16x4 __attribute__((ext_vector_type(4)));
typedef unsigned int u32x4 __attribute__((ext_vector_type(4)));

static __device__ __forceinline__ unsigned short f2bf(float f) {
  unsigned u = __float_as_uint(f);
  u += 0x7fffu + ((u >> 16) & 1u);
  return (unsigned short)(u >> 16);
}
static __device__ __forceinline__ float bf2f(unsigned short h) {
  return __uint_as_float(((unsigned)h) << 16);
}
static __device__ __forceinline__ float fast_exp2(float x) {
#if __has_builtin(__builtin_amdgcn_exp2f)
  return __builtin_amdgcn_exp2f(x);
#else
  return __expf(x * 0.6931471805599453f);
#endif
}
static __device__ __forceinline__ float fast_rcp(float x) {
#if __has_builtin(__builtin_amdgcn_rcpf)
  return __builtin_amdgcn_rcpf(x);
#else
  return 1.0f / x;
#endif
}
static __device__ __forceinline__ void dma16(const void* g, void* l) {
  __builtin_amdgcn_global_load_lds(
      (const __attribute__((address_space(1))) unsigned int*)(uintptr_t)g,
      (__attribute__((address_space(3))) unsigned int*)(uintptr_t)l, 16, 0, 0);
}
static __device__ __forceinline__ void dma4(const void* g, void* l) {
  __builtin_amdgcn_global_load_lds(
      (const __attribute__((address_space(1))) unsigned int*)(uintptr_t)g,
      (__attribute__((address_space(3))) unsigned int*)(uintptr_t)l, 4, 0, 0);
}
static __device__ __forceinline__ void barrier_plain() {
  __asm__ volatile("" ::: "memory");
  __builtin_amdgcn_s_barrier();
  __asm__ volatile("" ::: "memory");
}
#define WAITVM(N) __asm__ volatile("s_waitcnt vmcnt(" #N ")" ::: "memory")

// ---- ws layout (bytes) ----
#define XHI_OFF  0ull
#define XLO_OFF  16777216ull
#define KHI_OFF  33554432ull
#define VT_OFF   50331648ull
#define WHI_OFF  67108864ull
#define WLO_OFF  69206016ull
#define MB_OFF   71303168ull

// QSC = (1/32) * log2(e); exp2 shift = 8*log2(e)
#define QSC  0.0450842399f
#define ESHIFT 11.5415601730f

// ---------------- fused prep (unchanged) ----------------
__global__ __launch_bounds__(256) void prep_all(const float* __restrict__ Kg,
                                                const float* __restrict__ Vg,
                                                const float* __restrict__ Wg,
                                                const int* __restrict__ Mg,
                                                unsigned short* __restrict__ Khi,
                                                unsigned short* __restrict__ Vt,
                                                unsigned short* __restrict__ Whi,
                                                unsigned short* __restrict__ Wlo,
                                                unsigned long long* __restrict__ bits) {
  __shared__ unsigned short lds[64 * 66];
  const int tid = threadIdx.x;
  const int bid = blockIdx.x;
  if (bid < 8192) {
    // K f32 -> bf16 tiles [n][h][kt]{row=kvl, 128B rows, chunk c stored at c^(row&7)}
    int t = bid * 256 + tid;
    int d4 = t & 15, h = (t >> 4) & 15, kv = (t >> 8) & 2047, n = t >> 19;
    f32x4 a = *(const f32x4*)(Kg + (size_t)(n * KL + kv) * EMB + h * 64 + d4 * 4);
    u16x4 o;
    #pragma unroll
    for (int j = 0; j < 4; ++j) o[j] = f2bf(a[j]);
    int row = kv & 63, c0 = d4 >> 1;
    int pos = row * 128 + ((c0 ^ (row & 7)) << 4) + (d4 & 1) * 8;
    size_t slab = (size_t)((n * 16 + h) * 32 + (kv >> 6)) * 8192;
    *(u16x4*)((char*)Khi + slab + pos) = o;
  } else if (bid < 10240) {
    // V -> V^T bf16 tiles, pi(kv) column permute (swap bits 2<->3), fetch-swizzled rows
    int vb = bid - 8192;
    int kt = vb & 31, h = (vb >> 5) & 15, n = vb >> 9;
    #pragma unroll
    for (int i = 0; i < 4; ++i) {
      int e = i * 256 + tid;
      int d4 = e & 15, kvl = e >> 4;
      int col = (kvl & 48) | (kvl & 3) | ((kvl & 4) << 1) | ((kvl & 8) >> 1);
      f32x4 a = *(const f32x4*)(Vg + (size_t)(n * KL + kt * 64 + kvl) * EMB + h * 64 + d4 * 4);
      #pragma unroll
      for (int j = 0; j < 4; ++j) lds[(d4 * 4 + j) * 66 + col] = f2bf(a[j]);
    }
    __syncthreads();
    size_t slab = (size_t)((n * 16 + h) * 32 + kt) * 8192;
    #pragma unroll
    for (int i = 0; i < 4; ++i) {
      int e = i * 256 + tid;
      int kv4 = e & 15, d = e >> 4;
      u16x4 o;
      #pragma unroll
      for (int j = 0; j < 4; ++j) o[j] = lds[d * 66 + kv4 * 4 + j];
      int c0 = kv4 >> 1;
      int pos = d * 128 + ((c0 ^ (d & 7)) << 4) + (kv4 & 1) * 8;
      *(u16x4*)((char*)Vt + slab + pos) = o;
    }
  } else if (bid < 11264) {
    // W -> hi/lo split, flat
    int t = (bid - 10240) * 256 + tid;
    int c4 = t & 255, row = t >> 8;
    f32x4 a = *(const f32x4*)(Wg + (size_t)row * 1024 + c4 * 4);
    u16x4 hi, lo;
    #pragma unroll
    for (int j = 0; j < 4; ++j) {
      unsigned short hb = f2bf(a[j]);
      hi[j] = hb;
      lo[j] = f2bf(a[j] - bf2f(hb));
    }
    *(u16x4*)(Whi + (size_t)row * 1024 + c4 * 4) = hi;
    *(u16x4*)(Wlo + (size_t)row * 1024 + c4 * 4) = lo;
  } else {
    // mask int32 -> bit words, relaid out [n][qb(8)][kt(32)][q(256)]; 2 words per wave
    int t = (bid - 11264) * 256 + tid;
    int l = t & 63;
    int W = t >> 6;                       // wave id: 0..131071
    int kw2 = (W & 15) * 2;
    int row = W >> 4;                     // n*QL + q
    const int* mp = Mg + (size_t)row * KL;
    int v0 = mp[kw2 * 64 + l];
    int v1 = mp[kw2 * 64 + 64 + l];
    unsigned long long b0 = __ballot(v0 != 0);
    unsigned long long b1 = __ballot(v1 != 0);
    int q = row & 2047, nn = row >> 11;
    size_t base = (size_t)((nn * 8 + (q >> 8)) * 32) * 256 + (q & 255);
    if (l == 0) {
      bits[base + (size_t)kw2 * 256] = b0;
      bits[base + (size_t)(kw2 + 1) * 256] = b1;
    }
  }
}

// ---------------- flash attention: S^T trick, 64 q per wave, manual dbuf pipeline ----------------
// block = 4 waves x 64 q = 256 q; grid = 4*16*8 = 512 (= 2 blocks/CU, grid-limited)
// EXACT round-0 structure (proven 107us, 120 VGPR no-spill at bounds(256,2)).
// Additions only: bijective XCD blockIdx swizzle (proven FETCH 148->53MB) and
// s_setprio around MFMA clusters (independent-block waves per SIMD -> arbitration).
// DO NOT raise the launch_bounds min-waves: >=3 forces VGPR cap < 120 live state
// -> scratch spill -> 10x regression (round-3 postmortem, FETCH 2GB).
__global__ __launch_bounds__(256, 2) void attn4(const float* __restrict__ Qg,
                                                const unsigned short* __restrict__ Khi,
                                                const unsigned short* __restrict__ Vt,
                                                const unsigned long long* __restrict__ Mb,
                                                unsigned short* __restrict__ Xhi,
                                                unsigned short* __restrict__ Xlo) {
  __shared__ __align__(16) char smem[2 * 18432];  // per buf: K 8K | V 8K | M 2K
  const int tid = threadIdx.x;
  const int w = tid >> 6;
  const int l = tid & 63;
  const int q32 = l & 31;
  const int h5 = l >> 5;
  const int bid0 = blockIdx.x;
  // bijective XCD swizzle: 512 % 8 == 0; each XCD gets 64 contiguous logical
  // blocks = 8 (n,h) K/V slab pairs (4MB) -> per-XCD L2 resident
  const int bid = (bid0 & 7) * 64 + (bid0 >> 3);
  const int qb = bid & 7;
  const int h = (bid >> 3) & 15;
  const int n = bid >> 7;
  const int qbase = qb * 256 + w * 64;

  const char* kslab = (const char*)Khi + (size_t)(n * HEADS + h) * 262144;
  const char* vslab = (const char*)Vt + (size_t)(n * HEADS + h) * 262144;
  const char* mslab = (const char*)Mb + (size_t)(n * 8 + qb) * 65536;

  // Q fragments (B-operand), prescaled by QSC; two 32-q column groups per wave
  bf16x8 qh[2][4];
  #pragma unroll
  for (int c = 0; c < 2; ++c) {
    const float* qp = Qg + (size_t)(n * QL + qbase + c * 32 + q32) * EMB + h * HD + h5 * 8;
    #pragma unroll
    for (int kc = 0; kc < 4; ++kc) {
      union { u16x8 u; bf16x8 b; } H;
      #pragma unroll
      for (int j = 0; j < 8; ++j) H.u[j] = f2bf(qp[kc * 16 + j] * QSC);
      qh[c][kc] = H.b;
    }
  }
  WAITVM(0);  // no VGPR-returning vmem outstanding before DMA pipeline starts

  // hoisted LDS offsets: off8[r2][g] for row = r2*32+q32, chunk G = 2g+h5
  int off8[2][4];
  #pragma unroll
  for (int r2 = 0; r2 < 2; ++r2)
    #pragma unroll
    for (int g = 0; g < 4; ++g)
      off8[r2][g] = (r2 * 32 + q32) * 128 + (((2 * g + h5) ^ (q32 & 7)) << 4);

  f32x16 o00, o01, o10, o11, l0, l1;
  #pragma unroll
  for (int i = 0; i < 16; ++i) {
    o00[i] = 0.f; o01[i] = 0.f; o10[i] = 0.f; o11[i] = 0.f; l0[i] = 0.f; l1[i] = 0.f;
  }

  union { u16x8 u; bf16x8 b; } O1;
  #pragma unroll
  for (int j = 0; j < 8; ++j) O1.u[j] = 0x3F80;  // bf16 1.0
  const bf16x8 ones = O1.b;

  auto issue = [&](int kt, char* buf) {
    const char* ks = kslab + kt * 8192 + w * 2048 + l * 16;
    const char* vs = vslab + kt * 8192 + w * 2048 + l * 16;
    dma16(ks, buf + w * 2048);
    dma16(ks + 1024, buf + w * 2048 + 1024);
    dma16(vs, buf + 8192 + w * 2048);
    dma16(vs + 1024, buf + 8192 + w * 2048 + 1024);
    const char* ms = mslab + kt * 2048 + w * 512 + l * 4;
    dma4(ms, buf + 16384 + w * 512);
    dma4(ms + 256, buf + 16384 + w * 512 + 256);
  };

  auto step = [&](int kt, char* cur, char* nxt) {
    barrier_plain();                       // everyone done reading nxt's old tile
    if (kt != 31) {
      issue(kt + 1, nxt);
      WAITVM(6);                           // drain tile kt's 6 DMAs, keep kt+1's 6
    } else {
      WAITVM(0);
    }
    barrier_plain();                       // publish tile kt
    unsigned long long mwc0 = *(const unsigned long long*)(cur + 16384 + (w * 64 + q32) * 8);
    unsigned long long mwc1 = *(const unsigned long long*)(cur + 16384 + (w * 64 + 32 + q32) * 8);

    #pragma unroll
    for (int Mt = 0; Mt < 2; ++Mt) {
      // K fragments: shared across both q-groups
      union { u16x8 u; bf16x8 b; } kf[4];
      #pragma unroll
      for (int kc = 0; kc < 4; ++kc) kf[kc].u = *(const u16x8*)(cur + off8[Mt][kc]);

      unsigned int pk0[8], pk1[8];
      #pragma unroll
      for (int c = 0; c < 2; ++c) {
        f32x16 st;
        #pragma unroll
        for (int i = 0; i < 16; ++i) st[i] = -ESHIFT;   // fold exp2 shift into C-init
        __builtin_amdgcn_s_setprio(1);
        #pragma unroll
        for (int kc = 0; kc < 4; ++kc)
          st = __builtin_amdgcn_mfma_f32_32x32x16_bf16(kf[kc].b, qh[c][kc], st, 0, 0, 0);
        __builtin_amdgcn_s_setprio(0);
        unsigned long long mwc = c ? mwc1 : mwc0;
        unsigned int half = (unsigned int)(Mt ? (mwc >> 32) : mwc) >> (h5 * 4);
        unsigned int* pk = c ? pk1 : pk0;
        #pragma unroll
        for (int i = 0; i < 8; ++i) {
          const int r0 = 2 * i;
          const int b0 = (r0 & 3) + 8 * (r0 >> 2);
          float a0 = ((half >> b0) & 1u) ? st[r0] : -1.0e38f;
          float a1 = ((half >> (b0 + 1)) & 1u) ? st[r0 + 1] : -1.0e38f;
          float p0 = fast_exp2(a0);
          float p1 = fast_exp2(a1);
          bf16x2 pv = __builtin_convertvector((f32x2){p0, p1}, bf16x2);
          unsigned int u;
          __builtin_memcpy(&u, &pv, 4);
          pk[i] = u;
        }
      }
      #pragma unroll
      for (int kc2 = 0; kc2 < 2; ++kc2) {
        const int kvc = Mt * 2 + kc2;
        union { u16x8 u; bf16x8 b; } vf0, vf1;   // shared across both q-groups
        vf0.u = *(const u16x8*)(cur + 8192 + off8[0][kvc]);
        vf1.u = *(const u16x8*)(cur + 8192 + off8[1][kvc]);
        union { u32x4 wv; bf16x8 b; } pf0, pf1;
        #pragma unroll
        for (int j = 0; j < 4; ++j) {
          pf0.wv[j] = pk0[4 * kc2 + j];
          pf1.wv[j] = pk1[4 * kc2 + j];
        }
        __builtin_amdgcn_s_setprio(1);
        o00 = __builtin_amdgcn_mfma_f32_32x32x16_bf16(pf0.b, vf0.b, o00, 0, 0, 0);
        o01 = __builtin_amdgcn_mfma_f32_32x32x16_bf16(pf0.b, vf1.b, o01, 0, 0, 0);
        l0  = __builtin_amdgcn_mfma_f32_32x32x16_bf16(pf0.b, ones,  l0,  0, 0, 0);
        o10 = __builtin_amdgcn_mfma_f32_32x32x16_bf16(pf1.b, vf0.b, o10, 0, 0, 0);
        o11 = __builtin_amdgcn_mfma_f32_32x32x16_bf16(pf1.b, vf1.b, o11, 0, 0, 0);
        l1  = __builtin_amdgcn_mfma_f32_32x32x16_bf16(pf1.b, ones,  l1,  0, 0, 0);
        __builtin_amdgcn_s_setprio(0);
      }
    }
  };

  issue(0, smem);
  for (int kt2 = 0; kt2 < 16; ++kt2) {
    step(2 * kt2, smem, smem + 18432);
    step(2 * kt2 + 1, smem + 18432, smem);
  }

  // epilogue: per-reg l from ones-MFMA, rcp, split hi/lo
  #pragma unroll
  for (int c = 0; c < 2; ++c) {
    const f32x16& oa = c ? o10 : o00;
    const f32x16& ob = c ? o11 : o01;
    const f32x16& ll = c ? l1 : l0;
    #pragma unroll
    for (int r = 0; r < 16; ++r) {
      float inv = fast_rcp(ll[r]);
      int qr = (r & 3) + 8 * (r >> 2) + 4 * h5;
      size_t base = (size_t)(n * QL + qbase + c * 32 + qr) * EMB + h * HD + q32;
      float v0 = oa[r] * inv;
      unsigned short h0 = f2bf(v0);
      Xhi[base] = h0;
      Xlo[base] = f2bf(v0 - bf2f(h0));
      float v1 = ob[r] * inv;
      unsigned short h1 = f2bf(v1);
      Xhi[base + 32] = h1;
      Xlo[base + 32] = f2bf(v1 - bf2f(h1));
    }
  }
}

// ---------------- out = X @ W^T + b, split-bf16 3-term, manual dbuf pipeline ----------------
__global__ __launch_bounds__(256, 2) void proj3(const unsigned short* __restrict__ Xhi,
                                                const unsigned short* __restrict__ Xlo,
                                                const unsigned short* __restrict__ Whi,
                                                const unsigned short* __restrict__ Wlo,
                                                const float* __restrict__ bias,
                                                float* __restrict__ out) {
  __shared__ __align__(16) char pm[65536];   // 2 x (Ah|Al|Bh|Bl), 8KB each
  const int tid = threadIdx.x;
  const int w = tid >> 6;
  const int l = tid & 63;
  const int lr = l & 15;
  const int lq = l >> 4;
  const int wm = w >> 1, wn = w & 1;
  const int bid = blockIdx.x;
  const int m0 = (bid >> 3) * 128;
  const int n0 = (bid & 7) * 128;

  f32x4 acc[4][4];
  #pragma unroll
  for (int i = 0; i < 4; ++i)
    #pragma unroll
    for (int j = 0; j < 4; ++j) acc[i][j] = (f32x4){0.f, 0.f, 0.f, 0.f};

  auto issue = [&](int kc, char* buf) {
    #pragma unroll
    for (int i = 0; i < 8; ++i) {
      int s = (i * 256 + tid) * 16;
      int sel = s >> 13;
      int s2 = s & 8191;
      int row = s2 >> 6;
      int c = (s2 >> 4) & 3;
      const unsigned short* pl = sel == 0 ? Xhi : sel == 1 ? Xlo : sel == 2 ? Whi : Wlo;
      int rbase = (sel < 2 ? m0 : n0) + row;
      dma16(pl + (size_t)rbase * 1024 + kc * 32 + c * 8, buf + i * 4096 + w * 1024);
    }
  };

  auto pstep = [&](int kc, char* cur, char* nxt) {
    barrier_plain();
    if (kc != 31) {
      issue(kc + 1, nxt);
      WAITVM(8);
    } else {
      WAITVM(0);
    }
    barrier_plain();

    bf16x8 ah[4], al[4], bh[4], bl[4];
    #pragma unroll
    for (int mt = 0; mt < 4; ++mt) {
      int off = (wm * 64 + mt * 16 + lr) * 64 + lq * 16;
      union { u16x8 u; bf16x8 b; } A, B;
      A.u = *(const u16x8*)(cur + off);
      B.u = *(const u16x8*)(cur + 8192 + off);
      ah[mt] = A.b;
      al[mt] = B.b;
    }
    #pragma unroll
    for (int nt = 0; nt < 4; ++nt) {
      int off = (wn * 64 + nt * 16 + lr) * 64 + lq * 16;
      union { u16x8 u; bf16x8 b; } A, B;
      A.u = *(const u16x8*)(cur + 16384 + off);
      B.u = *(const u16x8*)(cur + 24576 + off);
      bh[nt] = A.b;
      bl[nt] = B.b;
    }
    #pragma unroll
    for (int mt = 0; mt < 4; ++mt)
      #pragma unroll
      for (int nt = 0; nt < 4; ++nt) {
        f32x4 c = acc[mt][nt];
        c = __builtin_amdgcn_mfma_f32_16x16x32_bf16(ah[mt], bh[nt], c, 0, 0, 0);
        c = __builtin_amdgcn_mfma_f32_16x16x32_bf16(ah[mt], bl[nt], c, 0, 0, 0);
        c = __builtin_amdgcn_mfma_f32_16x16x32_bf16(al[mt], bh[nt], c, 0, 0, 0);
        acc[mt][nt] = c;
      }
  };

  issue(0, pm);
  for (int kc2 = 0; kc2 < 16; ++kc2) {
    pstep(2 * kc2, pm, pm + 32768);
    pstep(2 * kc2 + 1, pm + 32768, pm);
  }

  #pragma unroll
  for (int nt = 0; nt < 4; ++nt) {
    int col = n0 + wn * 64 + nt * 16 + lr;
    float bv = bias[col];
    #pragma unroll
    for (int mt = 0; mt < 4; ++mt) {
      int rowb = m0 + wm * 64 + mt * 16 + lq * 4;
      #pragma unroll
      for (int r = 0; r < 4; ++r)
        out[(size_t)(rowb + r) * EMB + col] = acc[mt][nt][r] + bv;
    }
  }
}

extern "C" void kernel_launch(void* const* d_in, const int* in_sizes, int n_in,
                              void* d_out, int out_size, void* d_ws, size_t ws_size,
                              hipStream_t stream) {
  const float* Qg = (const float*)d_in[0];
  const float* Kg = (const float*)d_in[1];
  const float* Vg = (const float*)d_in[2];
  const int* Mg = (const int*)d_in[3];
  const float* Wg = (const float*)d_in[4];
  const float* Bg = (const float*)d_in[5];
  float* out = (float*)d_out;

  char* ws = (char*)d_ws;
  unsigned short* xhi = (unsigned short*)(ws + XHI_OFF);
  unsigned short* xlo = (unsigned short*)(ws + XLO_OFF);
  unsigned short* khi = (unsigned short*)(ws + KHI_OFF);
  unsigned short* vt = (unsigned short*)(ws + VT_OFF);
  unsigned short* whi = (unsigned short*)(ws + WHI_OFF);
  unsigned short* wlo = (unsigned short*)(ws + WLO_OFF);
  unsigned long long* mbits = (unsigned long long*)(ws + MB_OFF);

  prep_all<<<44032, 256, 0, stream>>>(Kg, Vg, Wg, Mg, khi, vt, whi, wlo, mbits);
  attn4<<<NB * HEADS * (QL / 256), 256, 0, stream>>>(Qg, khi, vt, mbits, xhi, xlo);
  proj3<<<(NB * QL / 128) * (EMB / 128), 256, 0, stream>>>(xhi, xlo, whi, wlo, Bg, out);
}